// Round 2
// baseline (127.343 us; speedup 1.0000x reference)
//
#include <hip/hip_runtime.h>

#define EPSILON 1e-6f
#define NADMIN 256
#define NBATCH 16
#define NPIX (1024 * 1024)   // H*W per batch
#define NCOPY 32             // histogram copies (one per bank)

// ---------------------------------------------------------------------------
// Pass 1: per-batch segment sum into S[b][a].
// Bank-aligned privatized histogram: s_hist[bin][copy], copy = lane&31.
// Address = bin*32 + copy -> bank = copy -> every atomic lands in its own
// bank regardless of bin. Same-address collision only lanes 32 apart w/ same
// bin (~1/256) - handled by HW atomic.
// grid = (128, NBATCH), block = 256
// ---------------------------------------------------------------------------
__global__ __launch_bounds__(256) void segsum_kernel(
    const float* __restrict__ P,
    const int* __restrict__ ids,
    float* __restrict__ S)
{
    __shared__ float s_hist[NADMIN][NCOPY];   // 32 KB
    const int b = blockIdx.y;
    const int t = threadIdx.x;

    for (int i = t; i < NADMIN * NCOPY; i += 256) ((float*)s_hist)[i] = 0.0f;
    __syncthreads();

    const int copy = t & 31;
    const float4* __restrict__ p4  = (const float4*)(P   + (size_t)b * NPIX);
    const int4*   __restrict__ id4 = (const int4*)  (ids + (size_t)b * NPIX);
    const int nvec = NPIX / 4;                // 262144
    const int stride = gridDim.x * blockDim.x;

    int i = blockIdx.x * blockDim.x + t;
    // 4x unrolled: issue 8 vector loads (128B) before any atomic -> MLP.
    for (; i + 3 * stride < nvec; i += 4 * stride) {
        float4 pa = p4[i];
        int4   da = id4[i];
        float4 pb = p4[i + stride];
        int4   db = id4[i + stride];
        float4 pc = p4[i + 2 * stride];
        int4   dc = id4[i + 2 * stride];
        float4 pd = p4[i + 3 * stride];
        int4   dd = id4[i + 3 * stride];

        if (da.x >= 0) atomicAdd(&s_hist[da.x][copy], pa.x);
        if (da.y >= 0) atomicAdd(&s_hist[da.y][copy], pa.y);
        if (da.z >= 0) atomicAdd(&s_hist[da.z][copy], pa.z);
        if (da.w >= 0) atomicAdd(&s_hist[da.w][copy], pa.w);
        if (db.x >= 0) atomicAdd(&s_hist[db.x][copy], pb.x);
        if (db.y >= 0) atomicAdd(&s_hist[db.y][copy], pb.y);
        if (db.z >= 0) atomicAdd(&s_hist[db.z][copy], pb.z);
        if (db.w >= 0) atomicAdd(&s_hist[db.w][copy], pb.w);
        if (dc.x >= 0) atomicAdd(&s_hist[dc.x][copy], pc.x);
        if (dc.y >= 0) atomicAdd(&s_hist[dc.y][copy], pc.y);
        if (dc.z >= 0) atomicAdd(&s_hist[dc.z][copy], pc.z);
        if (dc.w >= 0) atomicAdd(&s_hist[dc.w][copy], pc.w);
        if (dd.x >= 0) atomicAdd(&s_hist[dd.x][copy], pd.x);
        if (dd.y >= 0) atomicAdd(&s_hist[dd.y][copy], pd.y);
        if (dd.z >= 0) atomicAdd(&s_hist[dd.z][copy], pd.z);
        if (dd.w >= 0) atomicAdd(&s_hist[dd.w][copy], pd.w);
    }
    for (; i < nvec; i += stride) {           // tail (empty for exact 8 iters)
        float4 p = p4[i];
        int4   d = id4[i];
        if (d.x >= 0) atomicAdd(&s_hist[d.x][copy], p.x);
        if (d.y >= 0) atomicAdd(&s_hist[d.y][copy], p.y);
        if (d.z >= 0) atomicAdd(&s_hist[d.z][copy], p.z);
        if (d.w >= 0) atomicAdd(&s_hist[d.w][copy], p.w);
    }
    __syncthreads();

    // Reduce 32 copies per bin. Rotated read (bin+j)&31 keeps it
    // conflict-free (bank = (bin+j)&31, distinct across lanes mod 32).
    for (int bin = t; bin < NADMIN; bin += 256) {
        float sum = 0.0f;
        #pragma unroll
        for (int j = 0; j < NCOPY; ++j) sum += s_hist[bin][(bin + j) & 31];
        if (sum != 0.0f) atomicAdd(&S[b * NADMIN + bin], sum);
    }
}

// ---------------------------------------------------------------------------
// Pass 2 (fused ratio + apply): out = valid ? p * census[id]/(S[id]+eps) : p
// grid = (128, NBATCH), block = 256
// ---------------------------------------------------------------------------
__global__ __launch_bounds__(256) void apply_kernel(
    const float* __restrict__ P,
    const int* __restrict__ ids,
    const float* __restrict__ S,
    const float* __restrict__ census,
    float* __restrict__ out)
{
    __shared__ float s_R[NADMIN];
    const int b = blockIdx.y;
    const int t = threadIdx.x;
    if (t < NADMIN)
        s_R[t] = census[b * NADMIN + t] / (S[b * NADMIN + t] + EPSILON);
    __syncthreads();

    const float4* __restrict__ p4  = (const float4*)(P   + (size_t)b * NPIX);
    const int4*   __restrict__ id4 = (const int4*)  (ids + (size_t)b * NPIX);
    float4* __restrict__ o4 = (float4*)(out + (size_t)b * NPIX);
    const int nvec = NPIX / 4;
    const int stride = gridDim.x * blockDim.x;

    for (int i = blockIdx.x * blockDim.x + t; i < nvec; i += stride) {
        float4 p = p4[i];
        int4   d = id4[i];
        float4 o;
        o.x = (d.x >= 0) ? p.x * s_R[d.x] : p.x;
        o.y = (d.y >= 0) ? p.y * s_R[d.y] : p.y;
        o.z = (d.z >= 0) ? p.z * s_R[d.z] : p.z;
        o.w = (d.w >= 0) ? p.w * s_R[d.w] : p.w;
        o4[i] = o;
    }
}

extern "C" void kernel_launch(void* const* d_in, const int* in_sizes, int n_in,
                              void* d_out, int out_size, void* d_ws, size_t ws_size,
                              hipStream_t stream)
{
    const float* P      = (const float*)d_in[0];   // (B,1,H,W) f32
    const int*   ids    = (const int*)d_in[1];     // (B,H,W) i32
    const float* census = (const float*)d_in[2];   // (B,A) f32
    float* out = (float*)d_out;

    float* S = (float*)d_ws;                       // (B,A) segment sums

    hipMemsetAsync(S, 0, NBATCH * NADMIN * sizeof(float), stream);

    dim3 block(256);
    dim3 grid(128, NBATCH);

    segsum_kernel<<<grid, block, 0, stream>>>(P, ids, S);
    apply_kernel<<<grid, block, 0, stream>>>(P, ids, S, census, out);
}

// Round 4
// 121.969 us; speedup vs baseline: 1.0441x; 1.0441x over previous
//
#include <hip/hip_runtime.h>

#define EPSILON 1e-6f
#define NADMIN 256
#define NBATCH 16
#define NPIX (1024 * 1024)    // H*W per batch
#define SEG_BLOCKS 64         // segsum blocks per batch
#define SEG_THREADS 512       // 8 waves/block; 1024 blocks -> 32 waves/CU
#define UNROLL 4

// ---------------------------------------------------------------------------
// Pass 1: per-block private histogram -> plain store to Spart[b][block][a].
// NO global atomics, NO memset dependency: every output byte overwritten
// every call (graph-replay safe).
// 1 KB LDS histogram keeps full occupancy; 4x unrolled loads give 8x16B
// outstanding per wave (Little's law: latency-bound fix).
// grid = (SEG_BLOCKS, NBATCH), block = SEG_THREADS
// ---------------------------------------------------------------------------
__global__ __launch_bounds__(SEG_THREADS, 8) void segsum_kernel(
    const float* __restrict__ P,
    const int* __restrict__ ids,
    float* __restrict__ Spart)
{
    __shared__ float s_hist[NADMIN];
    const int b = blockIdx.y;
    const int t = threadIdx.x;

    if (t < NADMIN) s_hist[t] = 0.0f;
    __syncthreads();

    const float4* __restrict__ p4  = (const float4*)(P   + (size_t)b * NPIX);
    const int4*   __restrict__ id4 = (const int4*)  (ids + (size_t)b * NPIX);
    const int nvec = NPIX / 4;                      // 262144
    const int stride = gridDim.x * blockDim.x;      // 32768

    int i = blockIdx.x * blockDim.x + t;
    for (; i + (UNROLL - 1) * stride < nvec; i += UNROLL * stride) {
        float4 p[UNROLL];
        int4   d[UNROLL];
        #pragma unroll
        for (int u = 0; u < UNROLL; ++u) {          // issue all loads first
            p[u] = p4[i + u * stride];
            d[u] = id4[i + u * stride];
        }
        #pragma unroll
        for (int u = 0; u < UNROLL; ++u) {
            if (d[u].x >= 0) atomicAdd(&s_hist[d[u].x], p[u].x);
            if (d[u].y >= 0) atomicAdd(&s_hist[d[u].y], p[u].y);
            if (d[u].z >= 0) atomicAdd(&s_hist[d[u].z], p[u].z);
            if (d[u].w >= 0) atomicAdd(&s_hist[d[u].w], p[u].w);
        }
    }
    for (; i < nvec; i += stride) {                 // tail (empty here)
        float4 p = p4[i];
        int4   d = id4[i];
        if (d.x >= 0) atomicAdd(&s_hist[d.x], p.x);
        if (d.y >= 0) atomicAdd(&s_hist[d.y], p.y);
        if (d.z >= 0) atomicAdd(&s_hist[d.z], p.z);
        if (d.w >= 0) atomicAdd(&s_hist[d.w], p.w);
    }
    __syncthreads();

    if (t < NADMIN)
        Spart[((size_t)b * SEG_BLOCKS + blockIdx.x) * NADMIN + t] = s_hist[t];
}

// ---------------------------------------------------------------------------
// Pass 2: R[b][a] = census[b][a] / (sum_j Spart[b][j][a] + eps).
// Fixed summation order -> bitwise deterministic. Plain stores only.
// grid = NBATCH, block = NADMIN
// ---------------------------------------------------------------------------
__global__ __launch_bounds__(NADMIN) void reduce_kernel(
    const float* __restrict__ Spart,
    const float* __restrict__ census,
    float* __restrict__ R)
{
    const int b = blockIdx.x;
    const int a = threadIdx.x;
    const float* base = Spart + (size_t)b * SEG_BLOCKS * NADMIN + a;
    float sum = 0.0f;
    #pragma unroll 8
    for (int j = 0; j < SEG_BLOCKS; ++j) sum += base[j * NADMIN];
    R[b * NADMIN + a] = census[b * NADMIN + a] / (sum + EPSILON);
}

// ---------------------------------------------------------------------------
// Pass 3: out = valid ? p * R[b][id] : p   (R staged in LDS, 1 KB)
// grid = (128, NBATCH), block = 256   (exact round-2 form, passed twice)
// ---------------------------------------------------------------------------
__global__ __launch_bounds__(256) void apply_kernel(
    const float* __restrict__ P,
    const int* __restrict__ ids,
    const float* __restrict__ R,
    float* __restrict__ out)
{
    __shared__ float s_R[NADMIN];
    const int b = blockIdx.y;
    const int t = threadIdx.x;
    if (t < NADMIN) s_R[t] = R[b * NADMIN + t];
    __syncthreads();

    const float4* __restrict__ p4  = (const float4*)(P   + (size_t)b * NPIX);
    const int4*   __restrict__ id4 = (const int4*)  (ids + (size_t)b * NPIX);
    float4* __restrict__ o4 = (float4*)(out + (size_t)b * NPIX);
    const int nvec = NPIX / 4;
    const int stride = gridDim.x * blockDim.x;

    for (int i = blockIdx.x * blockDim.x + t; i < nvec; i += stride) {
        float4 p = p4[i];
        int4   d = id4[i];
        float4 o;
        o.x = (d.x >= 0) ? p.x * s_R[d.x] : p.x;
        o.y = (d.y >= 0) ? p.y * s_R[d.y] : p.y;
        o.z = (d.z >= 0) ? p.z * s_R[d.z] : p.z;
        o.w = (d.w >= 0) ? p.w * s_R[d.w] : p.w;
        o4[i] = o;
    }
}

extern "C" void kernel_launch(void* const* d_in, const int* in_sizes, int n_in,
                              void* d_out, int out_size, void* d_ws, size_t ws_size,
                              hipStream_t stream)
{
    const float* P      = (const float*)d_in[0];   // (B,1,H,W) f32
    const int*   ids    = (const int*)d_in[1];     // (B,H,W) i32
    const float* census = (const float*)d_in[2];   // (B,A) f32
    float* out = (float*)d_out;

    float* Spart = (float*)d_ws;                           // (B, SEG_BLOCKS, A) = 1 MB
    float* R     = Spart + (size_t)NBATCH * SEG_BLOCKS * NADMIN;  // (B, A)

    segsum_kernel<<<dim3(SEG_BLOCKS, NBATCH), dim3(SEG_THREADS), 0, stream>>>(P, ids, Spart);
    reduce_kernel<<<dim3(NBATCH), dim3(NADMIN), 0, stream>>>(Spart, census, R);
    apply_kernel<<<dim3(128, NBATCH), dim3(256), 0, stream>>>(P, ids, R, out);
}

// Round 5
// 93.891 us; speedup vs baseline: 1.3563x; 1.2990x over previous
//
#include <hip/hip_runtime.h>

#define EPSILON 1e-6f
#define NADMIN 256
#define NBATCH 16
#define NPIX (1024 * 1024)     // H*W per batch
#define NCHUNK 32              // segsum chunks (1-wave blocks) per batch
#define HISTROWS 257           // 256 bins + 1 dummy row for invalid ids
#define SEG_ITERS 64           // iterations per wave; 512 px per iter

typedef __attribute__((address_space(1))) const unsigned int gu32;
typedef __attribute__((address_space(3))) unsigned int lu32;

__device__ __forceinline__ void load_lds16(const void* g, void* l) {
    // async global->LDS, 16B per lane: lane i reads g_i (per-lane), writes
    // ldsbase + i*16 (base must be wave-uniform; our staging is linear).
    __builtin_amdgcn_global_load_lds((gu32*)g, (lu32*)l, 16, 0, 0);
}

// ---------------------------------------------------------------------------
// Pass 1: per-wave private histogram with NON-ATOMIC per-lane columns.
// hist[row][lane]: lanes never alias (addr%64 = lane); bank = lane&31 (2-way,
// free); same-lane RAW handled by in-order DS execution. Invalid ids -> dummy
// row 256. Staging via global_load_lds double-buffer + counted vmcnt(4):
// 8KB in flight per wave covers load latency despite 2-waves/CU occupancy.
// grid = (NCHUNK, NBATCH), block = 64 (one wave). ~74KB LDS -> 2 blocks/CU.
// ---------------------------------------------------------------------------
__global__ __launch_bounds__(64) void segsum_kernel(
    const float* __restrict__ P,
    const int* __restrict__ ids,
    float* __restrict__ Spart)
{
    __shared__ float  hist[HISTROWS * 64];   // 65792 B
    __shared__ float4 stP[2][128];           // 4 KB  (2 buf x 512 px)
    __shared__ int4   stI[2][128];           // 4 KB

    const int lane  = threadIdx.x;           // block == 1 wave
    const int b     = blockIdx.y;
    const int chunk = blockIdx.x;

    for (int i = lane; i < HISTROWS * 64; i += 64) hist[i] = 0.0f;

    // this wave's 32768 pixels = 8192 float4s, 128 float4 (512 px) per iter
    const float4* gP = (const float4*)(P   + (size_t)b * NPIX) + chunk * 8192;
    const int4*   gI = (const int4*)  (ids + (size_t)b * NPIX) + chunk * 8192;

    auto stage = [&](int buf, int it) {
        #pragma unroll
        for (int k = 0; k < 2; ++k) {
            load_lds16((const void*)(gP + it * 128 + k * 64 + lane),
                       (void*)&stP[buf][k * 64]);
            load_lds16((const void*)(gI + it * 128 + k * 64 + lane),
                       (void*)&stI[buf][k * 64]);
        }
    };

    stage(0, 0);
    stage(1, 1);

    for (int it = 0; it < SEG_ITERS; ++it) {
        const int cur = it & 1;
        // wait for current buffer's 4 loads (oldest); keep next buffer's 4
        // in flight. Only global_load_lds ops count against vmcnt here.
        if (it < SEG_ITERS - 2) asm volatile("s_waitcnt vmcnt(4)" ::: "memory");
        else                    asm volatile("s_waitcnt vmcnt(0)" ::: "memory");

        #pragma unroll
        for (int g = 0; g < 2; ++g) {
            float4 p = stP[cur][g * 64 + lane];   // ds_read_b128
            int4   d = stI[cur][g * 64 + lane];
            int r0 = (d.x >= 0) ? d.x : 256;  hist[r0 * 64 + lane] += p.x;
            int r1 = (d.y >= 0) ? d.y : 256;  hist[r1 * 64 + lane] += p.y;
            int r2 = (d.z >= 0) ? d.z : 256;  hist[r2 * 64 + lane] += p.z;
            int r3 = (d.w >= 0) ? d.w : 256;  hist[r3 * 64 + lane] += p.w;
        }
        if (it + 2 < SEG_ITERS) stage(cur, it + 2);
    }

    // Reduce 64 lane-columns per bin (rotated reads: bank (j+lane)&31, 2-way).
    #pragma unroll
    for (int k = 0; k < 4; ++k) {
        const int bin = k * 64 + lane;
        float s = 0.0f;
        for (int j = 0; j < 64; ++j) s += hist[bin * 64 + ((j + lane) & 63)];
        Spart[((size_t)b * NCHUNK + chunk) * NADMIN + bin] = s;
    }
}

// ---------------------------------------------------------------------------
// Pass 2: R[b][a] = census[b][a] / (sum_c Spart[b][c][a] + eps).
// Fixed order -> deterministic. Plain stores only.
// grid = NBATCH, block = NADMIN
// ---------------------------------------------------------------------------
__global__ __launch_bounds__(NADMIN) void reduce_kernel(
    const float* __restrict__ Spart,
    const float* __restrict__ census,
    float* __restrict__ R)
{
    const int b = blockIdx.x;
    const int a = threadIdx.x;
    const float* base = Spart + (size_t)b * NCHUNK * NADMIN + a;
    float sum = 0.0f;
    #pragma unroll 8
    for (int c = 0; c < NCHUNK; ++c) sum += base[c * NADMIN];
    R[b * NADMIN + a] = census[b * NADMIN + a] / (sum + EPSILON);
}

// ---------------------------------------------------------------------------
// Pass 3: out = valid ? p * R[b][id] : p   (unchanged; passed 3 rounds)
// grid = (128, NBATCH), block = 256
// ---------------------------------------------------------------------------
__global__ __launch_bounds__(256) void apply_kernel(
    const float* __restrict__ P,
    const int* __restrict__ ids,
    const float* __restrict__ R,
    float* __restrict__ out)
{
    __shared__ float s_R[NADMIN];
    const int b = blockIdx.y;
    const int t = threadIdx.x;
    if (t < NADMIN) s_R[t] = R[b * NADMIN + t];
    __syncthreads();

    const float4* __restrict__ p4  = (const float4*)(P   + (size_t)b * NPIX);
    const int4*   __restrict__ id4 = (const int4*)  (ids + (size_t)b * NPIX);
    float4* __restrict__ o4 = (float4*)(out + (size_t)b * NPIX);
    const int nvec = NPIX / 4;
    const int stride = gridDim.x * blockDim.x;

    for (int i = blockIdx.x * blockDim.x + t; i < nvec; i += stride) {
        float4 p = p4[i];
        int4   d = id4[i];
        float4 o;
        o.x = (d.x >= 0) ? p.x * s_R[d.x] : p.x;
        o.y = (d.y >= 0) ? p.y * s_R[d.y] : p.y;
        o.z = (d.z >= 0) ? p.z * s_R[d.z] : p.z;
        o.w = (d.w >= 0) ? p.w * s_R[d.w] : p.w;
        o4[i] = o;
    }
}

extern "C" void kernel_launch(void* const* d_in, const int* in_sizes, int n_in,
                              void* d_out, int out_size, void* d_ws, size_t ws_size,
                              hipStream_t stream)
{
    const float* P      = (const float*)d_in[0];   // (B,1,H,W) f32
    const int*   ids    = (const int*)d_in[1];     // (B,H,W) i32
    const float* census = (const float*)d_in[2];   // (B,A) f32
    float* out = (float*)d_out;

    float* Spart = (float*)d_ws;                            // (B, NCHUNK, A) = 512 KB
    float* R     = Spart + (size_t)NBATCH * NCHUNK * NADMIN; // (B, A)

    segsum_kernel<<<dim3(NCHUNK, NBATCH), dim3(64), 0, stream>>>(P, ids, Spart);
    reduce_kernel<<<dim3(NBATCH), dim3(NADMIN), 0, stream>>>(Spart, census, R);
    apply_kernel<<<dim3(128, NBATCH), dim3(256), 0, stream>>>(P, ids, R, out);
}